// Round 4
// baseline (306.921 us; speedup 1.0000x reference)
//
#include <hip/hip_runtime.h>

#define NTOT 65536   // B * NPG
#define DIM  512
#define BGR  64
#define NPG  1024
#define DROPN 512    // NPG - ceil(0.5 * NPG)
#define SLICES 8     // edge slices per graph (K2 parallelism)
#define DEG_BLOCKS 64      // one full-graph degree histogram block per graph
#define MV_BLOCKS 2048

typedef float vf4 __attribute__((ext_vector_type(4)));
typedef unsigned long long u64;

// ---- K1: blocks [0,64): per-graph FULL in-degree histogram (LDS) -> norm;
//      also zeroes agg + ticket for K2. blocks [64,2112): p = X@W wave-per-row ----
__global__ __launch_bounds__(256) void k1_matvec_deg(
        const float* __restrict__ X, const float* __restrict__ W,
        const int* __restrict__ dst,
        float* __restrict__ p, float* __restrict__ norm,
        float* __restrict__ agg, int* __restrict__ ticket, int epg) {
    __shared__ int dl[NPG];
    if (blockIdx.x < DEG_BLOCKS) {
        const int g = blockIdx.x;                    // 0..63
        const int nbase = g * NPG;
        for (int i = threadIdx.x; i < NPG; i += 256) dl[i] = 0;
        ((vf4*)(agg + nbase))[threadIdx.x] = (vf4){0.f, 0.f, 0.f, 0.f};  // 256*4 = NPG
        if (threadIdx.x == 0) ticket[g] = 0;
        __syncthreads();
        const int4* d4 = (const int4*)(dst + (size_t)g * epg);
        const int n4 = epg >> 2;
        for (int i = threadIdx.x; i < n4; i += 256) {
            int4 d = d4[i];
            atomicAdd(&dl[d.x - nbase], 1);
            atomicAdd(&dl[d.y - nbase], 1);
            atomicAdd(&dl[d.z - nbase], 1);
            atomicAdd(&dl[d.w - nbase], 1);
        }
        __syncthreads();
        for (int i = threadIdx.x; i < NPG; i += 256) {
            int d = dl[i];
            norm[nbase + i] = d > 0 ? rsqrtf((float)d) : 0.f;
        }
    } else {
        const int lane = threadIdx.x & 63;
        const int wid  = ((blockIdx.x - DEG_BLOCKS) * 256 + threadIdx.x) >> 6; // 0..8191
        const int nw   = (MV_BLOCKS * 256) >> 6;                               // 8192
        const vf4* wr = (const vf4*)W;
        const vf4 w0 = wr[lane], w1 = wr[lane + 64];
        for (int row = wid; row < NTOT; row += 2 * nw) {
            const int row2 = row + nw;                         // NTOT % (2*nw) == 0
            const vf4* xr0 = (const vf4*)(X + (size_t)row  * DIM);
            const vf4* xr1 = (const vf4*)(X + (size_t)row2 * DIM);
            vf4 a0 = xr0[lane], a1 = xr0[lane + 64];
            vf4 b0 = xr1[lane], b1 = xr1[lane + 64];
            vf4 m0 = a0 * w0 + a1 * w1;
            vf4 m1 = b0 * w0 + b1 * w1;
            float s0 = m0[0] + m0[1] + m0[2] + m0[3];
            float s1 = m1[0] + m1[1] + m1[2] + m1[3];
            #pragma unroll
            for (int off = 32; off > 0; off >>= 1) {
                s0 += __shfl_down(s0, off, 64);
                s1 += __shfl_down(s1, off, 64);
            }
            if (lane == 0) { p[row] = s0; p[row2] = s1; }
        }
    }
}

// ---- K2 (merged agg + topk): per (graph,slice) block: LDS scatter-sum of the
//      slice's edges; atomic-merge into global agg. The LAST slice block of
//      each graph (device-scope ticket) then runs the radix SELECT with its
//      256 threads (4 contiguous nodes each) and writes gate. Same threshold
//      and stable tie-break semantics as the verified R3 select. ----
__global__ __launch_bounds__(256) void k2_agg_topk(
        const int* __restrict__ src, const int* __restrict__ dst,
        const float* __restrict__ p, const float* __restrict__ norm,
        const float* __restrict__ bias,
        float* __restrict__ agg, int* __restrict__ ticket,
        float* __restrict__ gate, int epg) {
    __shared__ float hl[NPG];
    __shared__ float al[NPG];
    __shared__ unsigned int hist[256];
    __shared__ unsigned int selbin, selkp;
    __shared__ unsigned int wsum[4];
    __shared__ int lastFlag;
    const int b = blockIdx.x;
    const int g = b & (BGR - 1);
    const int slice = b >> 6;
    const int nbase = g * NPG;
    const int eps = epg / SLICES;
    const int t = threadIdx.x;
    // stage hn = p*norm in LDS (vf4: 256 threads x 4 floats = NPG)
    {
        const vf4* pv = (const vf4*)(p + nbase);
        const vf4* nv = (const vf4*)(norm + nbase);
        ((vf4*)hl)[t] = pv[t] * nv[t];
        ((vf4*)al)[t] = (vf4){0.f, 0.f, 0.f, 0.f};
    }
    __syncthreads();
    const int4* s4 = (const int4*)(src + (size_t)g * epg + (size_t)slice * eps);
    const int4* d4 = (const int4*)(dst + (size_t)g * epg + (size_t)slice * eps);
    const int n4 = eps >> 2;
    for (int i = t; i < n4; i += 256) {
        int4 s = s4[i];
        int4 d = d4[i];
        atomicAdd(&al[d.x - nbase], hl[s.x - nbase]);
        atomicAdd(&al[d.y - nbase], hl[s.y - nbase]);
        atomicAdd(&al[d.z - nbase], hl[s.z - nbase]);
        atomicAdd(&al[d.w - nbase], hl[s.w - nbase]);
    }
    __syncthreads();
    // merge slice partial into global agg (device-scope atomics)
    #pragma unroll
    for (int c = 0; c < 4; c++) {
        int i = t + 256 * c;
        atomicAdd(&agg[nbase + i], al[i]);
    }
    __threadfence();                                   // release our adds
    if (t == 0) lastFlag = (atomicAdd(&ticket[g], 1) == SLICES - 1);
    __syncthreads();
    if (!lastFlag) return;
    // ---- last block for this graph: radix select + gate write ----
    __threadfence();                                   // acquire side
    const float bb = bias[0];
    float w[4];
    unsigned int v[4];
    bool act[4];
    const vf4* nv = (const vf4*)(norm + nbase);
    vf4 nrm4 = nv[t];
    #pragma unroll
    for (int c = 0; c < 4; c++) {
        int i = 4 * t + c;
        float a = atomicAdd(&agg[nbase + i], 0.f);     // coherent RMW read
        float ww = a * nrm4[c] + bb;
        ww = ww > 0.f ? ww : 0.f;          // relu; w>=0 -> uint bits order-preserving
        w[c] = ww;
        v[c] = __float_as_uint(ww);
        act[c] = true;
    }
    unsigned int kp = DROPN;               // residual rank within active set
    unsigned int T = 0;                    // threshold value bits, built per pass
    const int lane = t & 63;
    const int wv   = t >> 6;
    #pragma unroll
    for (int shift = 24; shift >= 0; shift -= 8) {
        hist[t] = 0;
        __syncthreads();
        #pragma unroll
        for (int c = 0; c < 4; c++)
            if (act[c]) atomicAdd(&hist[(v[c] >> shift) & 255u], 1u);
        __syncthreads();
        if (t < 64) {                       // wave-0 inclusive scan, 4 bins/lane
            unsigned int h0 = hist[t*4], h1 = hist[t*4+1], h2 = hist[t*4+2], h3 = hist[t*4+3];
            unsigned int lsum = h0 + h1 + h2 + h3;
            unsigned int x = lsum;
            #pragma unroll
            for (int off = 1; off < 64; off <<= 1) {
                unsigned int y = (unsigned int)__shfl_up((int)x, off, 64);
                if (lane >= off) x += y;
            }
            unsigned int excl = x - lsum;
            hist[t*4]   = excl + h0;
            hist[t*4+1] = excl + h0 + h1;
            hist[t*4+2] = excl + h0 + h1 + h2;
            hist[t*4+3] = excl + h0 + h1 + h2 + h3;
        }
        __syncthreads();
        {
            unsigned int lo = (t == 0) ? 0u : hist[t-1];
            unsigned int hi = hist[t];
            if (lo <= kp && kp < hi) { selbin = (unsigned int)t; selkp = kp - lo; }
        }
        __syncthreads();
        const unsigned int sb = selbin;     // next selbin write is >=3 barriers away
        kp = selkp;
        #pragma unroll
        for (int c = 0; c < 4; c++)
            act[c] = act[c] && (((v[c] >> shift) & 255u) == sb);
        T |= sb << shift;
    }
    // act[c] == (v == T); kp = drops remaining among the equal set (lowest index first)
    int cnt = 0;
    int pre[4];
    #pragma unroll
    for (int c = 0; c < 4; c++) { pre[c] = cnt; cnt += act[c] ? 1 : 0; }
    int x = cnt;
    #pragma unroll
    for (int off = 1; off < 64; off <<= 1) {
        int y = __shfl_up(x, off, 64);
        if (lane >= off) x += y;
    }
    if (lane == 63) wsum[wv] = (unsigned int)x;
    __syncthreads();
    int base = 0;
    for (int i = 0; i < wv; i++) base += (int)wsum[i];
    const int excl = base + x - cnt;        // # act elements with node index < 4t
    vf4 gout;
    #pragma unroll
    for (int c = 0; c < 4; c++) {
        bool keep = act[c] ? ((unsigned int)(excl + pre[c]) >= kp) : (v[c] > T);
        gout[c] = keep ? w[c] : 0.f;
    }
    ((vf4*)(gate + nbase))[t] = gout;
}

// ---- K3: out[row,:] = X[row,:] * gate[row]; NT stores keep X L3-resident ----
__global__ __launch_bounds__(256) void k3_gate(
        const float* __restrict__ X, const float* __restrict__ gate,
        float* __restrict__ out) {
    const int lane = threadIdx.x & 63;
    const int nw   = (gridDim.x * blockDim.x) >> 6;
    const int wid  = (blockIdx.x * blockDim.x + threadIdx.x) >> 6;
    for (int row = wid; row < NTOT; row += nw) {
        float g = gate[row];
        vf4* o = (vf4*)(out + (size_t)row * DIM);
        if (g == 0.f) {                    // wave-uniform (whole wave = one row)
            vf4 z = (vf4){0.f, 0.f, 0.f, 0.f};
            __builtin_nontemporal_store(z, &o[lane]);
            __builtin_nontemporal_store(z, &o[lane + 64]);
        } else {
            const vf4* xr = (const vf4*)(X + (size_t)row * DIM);
            vf4 a = xr[lane] * g;
            vf4 c = xr[lane + 64] * g;
            __builtin_nontemporal_store(a, &o[lane]);
            __builtin_nontemporal_store(c, &o[lane + 64]);
        }
    }
}

extern "C" void kernel_launch(void* const* d_in, const int* in_sizes, int n_in,
                              void* d_out, int out_size, void* d_ws, size_t ws_size,
                              hipStream_t stream) {
    const float* X    = (const float*)d_in[0];
    const int*   src  = (const int*)d_in[1];
    const int*   dst  = (const int*)d_in[2];
    const float* W    = (const float*)d_in[3];
    const float* bias = (const float*)d_in[4];
    float* out = (float*)d_out;
    int E   = in_sizes[1];
    int epg = E / BGR;

    float* ws     = (float*)d_ws;
    float* p      = ws;                     // [N] f32
    float* norm   = ws + 1 * NTOT;          // [N] f32
    float* gate   = ws + 2 * NTOT;          // [N] f32
    float* agg    = ws + 3 * NTOT;          // [N] f32
    int*   ticket = (int*)(ws + 4 * NTOT);  // [BGR] i32

    k1_matvec_deg<<<DEG_BLOCKS + MV_BLOCKS, 256, 0, stream>>>(X, W, dst, p, norm, agg, ticket, epg);
    k2_agg_topk<<<BGR * SLICES, 256, 0, stream>>>(src, dst, p, norm, bias, agg, ticket, gate, epg);
    k3_gate<<<2048, 256, 0, stream>>>(X, gate, out);
}

// Round 5
// 279.322 us; speedup vs baseline: 1.0988x; 1.0988x over previous
//
#include <hip/hip_runtime.h>

#define NTOT 65536   // B * NPG
#define DIM  512
#define BGR  64
#define NPG  1024
#define DROPN 512    // NPG - ceil(0.5 * NPG)
#define SLICES 8     // edge slices per graph (K2 parallelism)
#define DEG_BLOCKS 64      // one full-graph degree histogram block per graph
#define MV_BLOCKS 2048
#define GPB 32       // gate blocks per graph in K34

typedef float vf4 __attribute__((ext_vector_type(4)));
typedef unsigned long long u64;

// ---- K1: blocks [0,64): per-graph FULL in-degree histogram (LDS) -> norm;
//      blocks [64,2112): p = X@W wave-per-row (BW-bound, ~134 MB X stream) ----
__global__ __launch_bounds__(256) void k1_matvec_deg(
        const float* __restrict__ X, const float* __restrict__ W,
        const int* __restrict__ dst,
        float* __restrict__ p, float* __restrict__ norm, int epg) {
    __shared__ int dl[NPG];
    if (blockIdx.x < DEG_BLOCKS) {
        const int g = blockIdx.x;                    // 0..63
        const int nbase = g * NPG;
        for (int i = threadIdx.x; i < NPG; i += 256) dl[i] = 0;
        __syncthreads();
        const int4* d4 = (const int4*)(dst + (size_t)g * epg);
        const int n4 = epg >> 2;
        for (int i = threadIdx.x; i < n4; i += 256) {
            int4 d = d4[i];
            atomicAdd(&dl[d.x - nbase], 1);
            atomicAdd(&dl[d.y - nbase], 1);
            atomicAdd(&dl[d.z - nbase], 1);
            atomicAdd(&dl[d.w - nbase], 1);
        }
        __syncthreads();
        for (int i = threadIdx.x; i < NPG; i += 256) {
            int d = dl[i];
            norm[nbase + i] = d > 0 ? rsqrtf((float)d) : 0.f;
        }
    } else {
        const int lane = threadIdx.x & 63;
        const int wid  = ((blockIdx.x - DEG_BLOCKS) * 256 + threadIdx.x) >> 6; // 0..8191
        const int nw   = (MV_BLOCKS * 256) >> 6;                               // 8192
        const vf4* wr = (const vf4*)W;
        const vf4 w0 = wr[lane], w1 = wr[lane + 64];
        for (int row = wid; row < NTOT; row += 2 * nw) {
            const int row2 = row + nw;                         // NTOT % (2*nw) == 0
            const vf4* xr0 = (const vf4*)(X + (size_t)row  * DIM);
            const vf4* xr1 = (const vf4*)(X + (size_t)row2 * DIM);
            vf4 a0 = xr0[lane], a1 = xr0[lane + 64];
            vf4 b0 = xr1[lane], b1 = xr1[lane + 64];
            vf4 m0 = a0 * w0 + a1 * w1;
            vf4 m1 = b0 * w0 + b1 * w1;
            float s0 = m0[0] + m0[1] + m0[2] + m0[3];
            float s1 = m1[0] + m1[1] + m1[2] + m1[3];
            #pragma unroll
            for (int off = 32; off > 0; off >>= 1) {
                s0 += __shfl_down(s0, off, 64);
                s1 += __shfl_down(s1, off, 64);
            }
            if (lane == 0) { p[row] = s0; p[row2] = s1; }
        }
    }
}

// ---- K2: per (graph,slice): hn staged in LDS; LDS scatter-sum of slice edges;
//      write agg partial. 512 blocks -> whole machine busy on edge phase. ----
__global__ __launch_bounds__(256) void k2_agg(
        const int* __restrict__ src, const int* __restrict__ dst,
        const float* __restrict__ p, const float* __restrict__ norm,
        float* __restrict__ agg_part, int epg) {
    __shared__ float hl[NPG];
    __shared__ float al[NPG];
    const int b = blockIdx.x;
    const int g = b & (BGR - 1);
    const int slice = b >> 6;
    const int nbase = g * NPG;
    const int eps = epg / SLICES;
    for (int i = threadIdx.x; i < NPG; i += 256) {
        hl[i] = p[nbase + i] * norm[nbase + i];
        al[i] = 0.f;
    }
    __syncthreads();
    const int4* s4 = (const int4*)(src + (size_t)g * epg + (size_t)slice * eps);
    const int4* d4 = (const int4*)(dst + (size_t)g * epg + (size_t)slice * eps);
    const int n4 = eps >> 2;
    for (int i = threadIdx.x; i < n4; i += 256) {
        int4 s = s4[i];
        int4 d = d4[i];
        atomicAdd(&al[d.x - nbase], hl[s.x - nbase]);
        atomicAdd(&al[d.y - nbase], hl[s.y - nbase]);
        atomicAdd(&al[d.z - nbase], hl[s.z - nbase]);
        atomicAdd(&al[d.w - nbase], hl[s.w - nbase]);
    }
    __syncthreads();
    float* op = agg_part + (size_t)slice * NTOT + nbase;
    for (int i = threadIdx.x; i < NPG; i += 256) op[i] = al[i];
}

// ---- K34 (merged select + gate): 2048 blocks, 32 per graph. Each block
//      REDUNDANTLY computes its graph's radix select (pure LDS+VALU, no
//      cross-block comm; agg_part drained by launch boundary), broadcasts
//      gate values via LDS, then gates its 32-row share with NT stores.
//      Select semantics identical to the R3/R4-verified rank-DROPN select. ----
__global__ __launch_bounds__(256) void k34_select_gate(
        const float* __restrict__ agg_part, const float* __restrict__ norm,
        const float* __restrict__ bias, const float* __restrict__ X,
        float* __restrict__ out) {
    __shared__ unsigned int hist[256];
    __shared__ unsigned int selbin, selkp;
    __shared__ unsigned int wsum[4];
    __shared__ float gw[NPG];
    const int b = blockIdx.x;
    const int g   = b >> 5;                 // 32 blocks per graph
    const int sub = b & (GPB - 1);
    const int t = threadIdx.x;
    const int lane = t & 63;
    const int wv   = t >> 6;
    const int nbase = g * NPG;
    // --- per-thread 4 contiguous nodes: w = relu(agg*norm + bias) ---
    const float bb = bias[0];
    float w[4];
    unsigned int v[4];
    bool act[4];
    vf4 nrm4 = ((const vf4*)(norm + nbase))[t];
    vf4 a4 = (vf4){0.f, 0.f, 0.f, 0.f};
    #pragma unroll
    for (int s = 0; s < SLICES; s++)
        a4 += ((const vf4*)(agg_part + (size_t)s * NTOT + nbase))[t];
    #pragma unroll
    for (int c = 0; c < 4; c++) {
        float ww = a4[c] * nrm4[c] + bb;
        ww = ww > 0.f ? ww : 0.f;          // relu; w>=0 -> uint bits order-preserving
        w[c] = ww;
        v[c] = __float_as_uint(ww);
        act[c] = true;
    }
    // --- 4-pass radix select of rank-DROPN threshold ---
    unsigned int kp = DROPN;               // residual rank within active set
    unsigned int T = 0;                    // threshold value bits, built per pass
    #pragma unroll
    for (int shift = 24; shift >= 0; shift -= 8) {
        hist[t] = 0;
        __syncthreads();
        #pragma unroll
        for (int c = 0; c < 4; c++)
            if (act[c]) atomicAdd(&hist[(v[c] >> shift) & 255u], 1u);
        __syncthreads();
        if (t < 64) {                       // wave-0 inclusive scan, 4 bins/lane
            unsigned int h0 = hist[t*4], h1 = hist[t*4+1], h2 = hist[t*4+2], h3 = hist[t*4+3];
            unsigned int lsum = h0 + h1 + h2 + h3;
            unsigned int x = lsum;
            #pragma unroll
            for (int off = 1; off < 64; off <<= 1) {
                unsigned int y = (unsigned int)__shfl_up((int)x, off, 64);
                if (lane >= off) x += y;
            }
            unsigned int excl = x - lsum;
            hist[t*4]   = excl + h0;
            hist[t*4+1] = excl + h0 + h1;
            hist[t*4+2] = excl + h0 + h1 + h2;
            hist[t*4+3] = excl + h0 + h1 + h2 + h3;
        }
        __syncthreads();
        {
            unsigned int lo = (t == 0) ? 0u : hist[t-1];
            unsigned int hi = hist[t];
            if (lo <= kp && kp < hi) { selbin = (unsigned int)t; selkp = kp - lo; }
        }
        __syncthreads();
        const unsigned int sb = selbin;     // next selbin write is >=3 barriers away
        kp = selkp;
        #pragma unroll
        for (int c = 0; c < 4; c++)
            act[c] = act[c] && (((v[c] >> shift) & 255u) == sb);
        T |= sb << shift;
    }
    // act[c] == (v == T); kp = drops remaining among equal set (lowest index first)
    int cnt = 0;
    int pre[4];
    #pragma unroll
    for (int c = 0; c < 4; c++) { pre[c] = cnt; cnt += act[c] ? 1 : 0; }
    int x = cnt;
    #pragma unroll
    for (int off = 1; off < 64; off <<= 1) {
        int y = __shfl_up(x, off, 64);
        if (lane >= off) x += y;
    }
    if (lane == 63) wsum[wv] = (unsigned int)x;
    __syncthreads();
    int base = 0;
    for (int i = 0; i < wv; i++) base += (int)wsum[i];
    const int excl = base + x - cnt;        // # act elements with node index < 4t
    #pragma unroll
    for (int c = 0; c < 4; c++) {
        bool keep = act[c] ? ((unsigned int)(excl + pre[c]) >= kp) : (v[c] > T);
        gw[4*t + c] = keep ? w[c] : 0.f;
    }
    __syncthreads();
    // --- gate rows [nbase + sub*32, +32): wave-per-row, 8 rows per wave ---
    for (int r = wv; r < 32; r += 4) {
        const int row = nbase + sub * 32 + r;
        const float gv = gw[sub * 32 + r];
        vf4* o = (vf4*)(out + (size_t)row * DIM);
        if (gv == 0.f) {                    // wave-uniform (whole wave = one row)
            vf4 z = (vf4){0.f, 0.f, 0.f, 0.f};
            __builtin_nontemporal_store(z, &o[lane]);
            __builtin_nontemporal_store(z, &o[lane + 64]);
        } else {
            const vf4* xr = (const vf4*)(X + (size_t)row * DIM);
            vf4 a = xr[lane] * gv;
            vf4 c2 = xr[lane + 64] * gv;
            __builtin_nontemporal_store(a, &o[lane]);
            __builtin_nontemporal_store(c2, &o[lane + 64]);
        }
    }
}

extern "C" void kernel_launch(void* const* d_in, const int* in_sizes, int n_in,
                              void* d_out, int out_size, void* d_ws, size_t ws_size,
                              hipStream_t stream) {
    const float* X    = (const float*)d_in[0];
    const int*   src  = (const int*)d_in[1];
    const int*   dst  = (const int*)d_in[2];
    const float* W    = (const float*)d_in[3];
    const float* bias = (const float*)d_in[4];
    float* out = (float*)d_out;
    int E   = in_sizes[1];
    int epg = E / BGR;

    float* ws       = (float*)d_ws;
    float* p        = ws;                       // [N] f32
    float* norm     = ws + 1 * NTOT;            // [N] f32
    float* agg_part = ws + 2 * NTOT;            // [SLICES][N] f32

    k1_matvec_deg<<<DEG_BLOCKS + MV_BLOCKS, 256, 0, stream>>>(X, W, dst, p, norm, epg);
    k2_agg<<<BGR * SLICES, 256, 0, stream>>>(src, dst, p, norm, agg_part, epg);
    k34_select_gate<<<BGR * GPB, 256, 0, stream>>>(agg_part, norm, bias, X, out);
}